// Round 2
// 1072.905 us; speedup vs baseline: 1.4023x; 1.4023x over previous
//
#include <hip/hip_runtime.h>

#define NNODES 50000
#define NEDGES 800000
#define HDIM 128
#define DOUT 64
#define NLAYERS 3
#define NEG_SLOPE 0.2f

#define NODE_OUT_ELEMS (NNODES * DOUT)             // 3,200,000
#define EDGE_OUT_ELEMS (NEDGES * 3)                // 2,400,000
#define GEMB_OFF (NODE_OUT_ELEMS + EDGE_OUT_ELEMS) // 5,600,000

typedef __attribute__((ext_vector_type(8))) short short8;
typedef __attribute__((ext_vector_type(4))) float f32x4;

__device__ __forceinline__ float bf2f(unsigned short u) {
    union { unsigned int i; float f; } v; v.i = ((unsigned int)u) << 16; return v.f;
}
__device__ __forceinline__ unsigned short f2bf(float f) {
    union { unsigned int i; float f; } v; v.f = f;
    unsigned int b = v.i;
    unsigned int r = (b + 0x7FFFu + ((b >> 16) & 1u)) >> 16;
    return (unsigned short)r;
}
__device__ __forceinline__ float leaky(float x) { return x > 0.f ? x : NEG_SLOPE * x; }

// Edge fetch: which=0 -> src, which=1 -> dst. iflag=1 -> int32, 0 -> int64.
__device__ __forceinline__ int eget(const int* e32, const int* iflag, int which, int e) {
    int idx = which * NEDGES + e;
    return (*iflag) ? e32[idx] : e32[2 * idx];
}

__global__ void zero_int_kernel(int* p, int n) {
    int i = blockIdx.x * 256 + threadIdx.x;
    if (i < n) p[i] = 0;
}
__global__ void zero_f32_kernel(float* p, int n) {
    int i = blockIdx.x * 256 + threadIdx.x;
    if (i < n) p[i] = 0.f;
}

__global__ void detect_f32_kernel(const unsigned short* xb, int* flag) {
    int hit = 0;
    for (int j = threadIdx.x; j < 4096; j += 256) {
        int e = (xb[j] >> 7) & 0xFF;
        if (e >= 0x90) hit = 1;
    }
    if (hit) atomicOr(flag, 1);
}
__global__ void detect_i64_kernel(const int* e32, int* flag) {
    int i = blockIdx.x * 256 + threadIdx.x;
    if (i < NEDGES) {
        if (e32[2 * i + 1] != 0) atomicOr(flag, 1);
    }
}

__global__ void cvt_kernel(const void* src, float* dst, int n, const int* f32flag) {
    int i = blockIdx.x * 256 + threadIdx.x;
    if (i < n)
        dst[i] = (*f32flag) ? ((const float*)src)[i]
                            : bf2f(((const unsigned short*)src)[i]);
}
__global__ void cvt_layerW_kernel(const void* gat_W, float* dst, int l,
                                  const int* f32flag) {
    int i = blockIdx.x * 256 + threadIdx.x;
    if (i < HDIM * HDIM) {
        size_t idx = (size_t)l * HDIM * HDIM + i;
        dst[i] = (*f32flag) ? ((const float*)gat_W)[idx]
                            : bf2f(((const unsigned short*)gat_W)[idx]);
    }
}

// ---------------------------------------------------------------------------
// Generic scalar GEMM kept only for N=64 (node MLP layer 2).
// ---------------------------------------------------------------------------
__global__ void gemm_any_kernel(const void* Av, int a_dyn, const void* Bv,
                                int b_pre_f32, const float* bias,
                                void* Cv, int out_f32,
                                int M, int N, int relu, const int* f32flag) {
    const int f32 = *f32flag;
    const int a_f32 = a_dyn ? f32 : 0;
    const int b_f32 = b_pre_f32 ? 1 : f32;
    __shared__ float sA[4 * 128];
    const int tid = threadIdx.x;
    const int rpb = 256 / N;
    const int row0 = blockIdx.x * rpb;

    for (int i = tid; i < rpb * 128; i += 256) {
        int r = i >> 7, k = i & 127;
        int gr = row0 + r;
        float v = 0.f;
        if (gr < M) {
            if (a_f32) v = ((const float*)Av)[(size_t)gr * 128 + k];
            else       v = bf2f(((const unsigned short*)Av)[(size_t)gr * 128 + k]);
        }
        sA[i] = v;
    }
    __syncthreads();

    const int r = tid / N, col = tid % N;
    const int row = row0 + r;
    if (row < M) {
        float acc = bias ? bias[col] : 0.f;
        const float* a = &sA[r * 128];
        if (b_f32) {
            const float* B = (const float*)Bv;
            for (int k = 0; k < 128; k++) acc += a[k] * B[(size_t)k * N + col];
        } else {
            const unsigned short* B = (const unsigned short*)Bv;
            for (int k = 0; k < 128; k++) acc += a[k] * bf2f(B[(size_t)k * N + col]);
        }
        if (relu) acc = fmaxf(acc, 0.f);
        if (out_f32) ((float*)Cv)[(size_t)row * N + col] = acc;
        else         ((unsigned short*)Cv)[(size_t)row * N + col] = f2bf(acc);
    }
}

// ---------------------------------------------------------------------------
// Tiled GEMM for N=128: 16 rows/block, 8 accumulators/thread.
// B traffic /8 vs gemm_any; sA reads are wave-uniform broadcasts.
// Accumulation order per output identical to gemm_any -> bit-identical.
// ---------------------------------------------------------------------------
__global__ __launch_bounds__(256) void gemm128_kernel(
    const void* Av, int a_dyn, const void* Bv, int b_pre_f32,
    const float* bias, void* Cv, int out_f32, int M, int relu,
    const int* f32flag) {
    const int f32 = *f32flag;
    const int a_f32 = a_dyn ? f32 : 0;
    const int b_f32 = b_pre_f32 ? 1 : f32;
    __shared__ float sA[16 * 128];
    const int tid = threadIdx.x;
    const int row0 = blockIdx.x * 16;

    for (int i = tid; i < 16 * 128; i += 256) {
        int r = i >> 7, k = i & 127;
        int gr = row0 + r;
        float v = 0.f;
        if (gr < M) {
            if (a_f32) v = ((const float*)Av)[(size_t)gr * 128 + k];
            else       v = bf2f(((const unsigned short*)Av)[(size_t)gr * 128 + k]);
        }
        sA[i] = v;
    }
    __syncthreads();

    const int col = tid & 127;
    const int rg  = tid >> 7;       // 0 or 1: rows rg*8 .. rg*8+7
    float acc[8];
    float b0 = bias ? bias[col] : 0.f;
    #pragma unroll
    for (int r8 = 0; r8 < 8; r8++) acc[r8] = b0;

    if (b_f32) {
        const float* B = (const float*)Bv;
        for (int k = 0; k < 128; k++) {
            float bv = B[(size_t)k * 128 + col];
            #pragma unroll
            for (int r8 = 0; r8 < 8; r8++)
                acc[r8] += sA[(rg * 8 + r8) * 128 + k] * bv;
        }
    } else {
        const unsigned short* B = (const unsigned short*)Bv;
        for (int k = 0; k < 128; k++) {
            float bv = bf2f(B[(size_t)k * 128 + col]);
            #pragma unroll
            for (int r8 = 0; r8 < 8; r8++)
                acc[r8] += sA[(rg * 8 + r8) * 128 + k] * bv;
        }
    }

    #pragma unroll
    for (int r8 = 0; r8 < 8; r8++) {
        int row = row0 + rg * 8 + r8;
        if (row < M) {
            float a = acc[r8];
            if (relu) a = fmaxf(a, 0.f);
            if (out_f32) ((float*)Cv)[(size_t)row * 128 + col] = a;
            else         ((unsigned short*)Cv)[(size_t)row * 128 + col] = f2bf(a);
        }
    }
}

__global__ void alpha_kernel(const unsigned short* xw,
                             const float* a_s, const float* a_d,
                             float* alpha_s, float* alpha_d) {
    int wave = threadIdx.x >> 6, lane = threadIdx.x & 63;
    int n = blockIdx.x * 4 + wave;
    if (n >= NNODES) return;
    float v0 = bf2f(xw[(size_t)n * HDIM + lane]);
    float v1 = bf2f(xw[(size_t)n * HDIM + 64 + lane]);
    float ds = v0 * a_s[lane] + v1 * a_s[64 + lane];
    float dd = v0 * a_d[lane] + v1 * a_d[64 + lane];
    for (int d = 32; d >= 1; d >>= 1) { ds += __shfl_xor(ds, d); dd += __shfl_xor(dd, d); }
    if (lane == 0) { alpha_s[n] = ds; alpha_d[n] = dd; }
}

// ---- CSR build (group edges by dst) ----
__global__ void count_kernel(const int* e32, const int* iflag, int* cnt) {
    int e = blockIdx.x * 256 + threadIdx.x;
    if (e < NEDGES) atomicAdd(&cnt[eget(e32, iflag, 1, e)], 1);
}
__global__ void scan1_kernel(const int* cnt, int* off, int* bsum) {
    __shared__ int s[256];
    int t = threadIdx.x, i = blockIdx.x * 256 + t;
    int v = (i < NNODES) ? cnt[i] : 0;
    s[t] = v;
    __syncthreads();
    for (int d = 1; d < 256; d <<= 1) {
        int add = (t >= d) ? s[t - d] : 0;
        __syncthreads();
        s[t] += add;
        __syncthreads();
    }
    if (i < NNODES) off[i] = s[t] - v;          // exclusive
    if (t == 255) bsum[blockIdx.x] = s[255];
}
__global__ void scan2_kernel(int* bsum, int nblk) {
    if (threadIdx.x == 0 && blockIdx.x == 0) {
        int run = 0;
        for (int c = 0; c < nblk; c++) { int t = bsum[c]; bsum[c] = run; run += t; }
    }
}
__global__ void scan3_kernel(int* off, const int* bsum) {
    int i = blockIdx.x * 256 + threadIdx.x;
    if (i < NNODES) off[i] += bsum[blockIdx.x];
}
// use_csr: also record dst + original edge id (only when workspace allows)
__global__ void fill_kernel(const int* e32, const int* iflag, const int* off,
                            int* cur, int* csr_src, int* csr_dst, int* csr_eid,
                            int use_csr) {
    int e = blockIdx.x * 256 + threadIdx.x;
    if (e < NEDGES) {
        int sidx = eget(e32, iflag, 0, e);
        int d = eget(e32, iflag, 1, e);
        int p = atomicAdd(&cur[d], 1);
        int pos = off[d] + p;
        csr_src[pos] = sidx;
        if (use_csr) {
            csr_dst[pos] = d;
            csr_eid[pos] = e;
        }
    }
}

// GAT aggregation (gather): one wave per node; h = relu(h + agg + b) in place.
// 64 lanes = 4 edge-slots x 16 feature-lanes: 4 edges in flight per iteration,
// one 16B vector load per lane, serial chain cut 4x vs scalar loop.
// Self-loop handled analytically (not in CSR).
__global__ void aggregate_kernel(const unsigned short* __restrict__ xw,
                                 const float* __restrict__ as_, const float* __restrict__ ad_,
                                 const int* __restrict__ off, const int* __restrict__ csr_src,
                                 const float* __restrict__ gat_b, unsigned short* __restrict__ h) {
    int wave = threadIdx.x >> 6, lane = threadIdx.x & 63;
    int n = blockIdx.x * 4 + wave;
    if (n >= NNODES) return;
    int o0 = off[n];
    int o1 = (n == NNODES - 1) ? NEDGES : off[n + 1];
    int deg = o1 - o0;
    float adn = ad_[n];
    float lself = leaky(as_[n] + adn);

    // running max over incoming-edge logits (lane-strided)
    float m = lself;
    for (int i = lane; i < deg; i += 64) {
        int s = csr_src[o0 + i];
        m = fmaxf(m, leaky(as_[s] + adn));
    }
    #pragma unroll
    for (int d = 32; d >= 1; d >>= 1) m = fmaxf(m, __shfl_xor(m, d));

    const int slot = lane >> 4;     // which of 4 concurrent edges
    const int l15  = lane & 15;     // feature group: 8 bf16 = 16B per lane
    float denom = 0.f;
    float acc[8];
    #pragma unroll
    for (int k = 0; k < 8; k++) acc[k] = 0.f;

    for (int i = slot; i < deg; i += 4) {
        int s = csr_src[o0 + i];
        float p = __expf(leaky(as_[s] + adn) - m);
        denom += p;
        uint4 rv = *(const uint4*)(xw + (size_t)s * HDIM + l15 * 8);
        const unsigned short* rp = (const unsigned short*)&rv;
        #pragma unroll
        for (int k = 0; k < 8; k++) acc[k] += p * bf2f(rp[k]);
    }
    // reduce across the 4 edge-slots (lane^16, lane^32)
    #pragma unroll
    for (int d = 16; d <= 32; d <<= 1) {
        denom += __shfl_xor(denom, d);
        #pragma unroll
        for (int k = 0; k < 8; k++) acc[k] += __shfl_xor(acc[k], d);
    }

    // self-loop (after the cross-slot reduce; all lanes hold full sums)
    float ps = __expf(lself - m);
    denom += ps;
    uint4 sv = *(const uint4*)(xw + (size_t)n * HDIM + l15 * 8);
    const unsigned short* sp = (const unsigned short*)&sv;
    #pragma unroll
    for (int k = 0; k < 8; k++) acc[k] += ps * bf2f(sp[k]);

    if (slot == 0) {
        float inv = 1.f / denom;
        size_t base = (size_t)n * HDIM + l15 * 8;
        uint4 hv = *(const uint4*)(h + base);
        const unsigned short* hp = (const unsigned short*)&hv;
        unsigned short outv[8];
        #pragma unroll
        for (int k = 0; k < 8; k++) {
            float hx = bf2f(hp[k]);
            float bx = gat_b[l15 * 8 + k];
            outv[k] = f2bf(fmaxf(hx + acc[k] * inv + bx, 0.f));
        }
        *(uint4*)(h + base) = *(uint4*)outv;
    }
}

// ---------------------------------------------------------------------------
// MFMA Edge MLP. use_csr=1: iterate edges in CSR (dst-grouped) order so the
// dst-half of the gather is sequential (~4 distinct rows per 64-edge tile);
// outputs routed via csr_eid. use_csr=0: original edge order (proven path).
// Per-edge arithmetic identical in both modes.
// ---------------------------------------------------------------------------
__global__ __launch_bounds__(256) void edge_mlp_mfma_kernel(
    const unsigned short* __restrict__ h,
    const int* __restrict__ e32, const int* __restrict__ iflag,
    const int* __restrict__ csr_src, const int* __restrict__ csr_dst,
    const int* __restrict__ csr_eid, int use_csr,
    const float* __restrict__ We1, const float* __restrict__ be1,
    const float* __restrict__ We2, const float* __restrict__ be2,
    float* __restrict__ eout)
{
    constexpr int KP = 256 + 8;
    __shared__ unsigned short lEF[64 * KP];       // 33,792 B
    __shared__ float part[64][4][3];              //  3,072 B

    const int tid  = threadIdx.x;
    const int wave = tid >> 6, lane = tid & 63;
    const int quad = lane >> 4, l15 = lane & 15;
    const int ncol0 = wave * 32;

    short8 bw[8][2];
    for (int kk = 0; kk < 8; kk++) {
        for (int nt = 0; nt < 2; nt++) {
            short8 t;
            int n = ncol0 + nt * 16 + l15;
            #pragma unroll
            for (int j = 0; j < 8; j++)
                t[j] = (short)f2bf(We1[(size_t)(kk * 32 + quad * 8 + j) * HDIM + n]);
            bw[kk][nt] = t;
        }
    }

    float w2[2][3], b1v[2];
    for (int nt = 0; nt < 2; nt++) {
        int n = ncol0 + nt * 16 + l15;
        b1v[nt] = be1[n];
        for (int c = 0; c < 3; c++) w2[nt][c] = We2[n * 3 + c];
    }
    float be2v[3];
    for (int c = 0; c < 3; c++) be2v[c] = be2[c];

    f32x4 vzero; vzero[0] = 0.f; vzero[1] = 0.f; vzero[2] = 0.f; vzero[3] = 0.f;

    const int ntiles = NEDGES / 64;               // 12500
    for (int tile = blockIdx.x; tile < ntiles; tile += gridDim.x) {
        const int p0 = tile * 64;
        for (int c = tid; c < 64 * 32; c += 256) {
            int r = c >> 5, ck = c & 31;
            int node;
            if (use_csr) node = (ck < 16) ? csr_src[p0 + r] : csr_dst[p0 + r];
            else         node = eget(e32, iflag, (ck < 16) ? 0 : 1, p0 + r);
            uint4 v = *(const uint4*)(h + (size_t)node * HDIM + (ck & 15) * 8);
            *(uint4*)(&lEF[r * KP + ck * 8]) = v;
        }
        __syncthreads();

        f32x4 acc[4][2];
        for (int mt = 0; mt < 4; mt++)
            for (int nt = 0; nt < 2; nt++)
                acc[mt][nt] = vzero;

        #pragma unroll
        for (int kk = 0; kk < 8; kk++) {
            short8 a[4];
            #pragma unroll
            for (int mt = 0; mt < 4; mt++)
                a[mt] = *(const short8*)(&lEF[(mt * 16 + l15) * KP + kk * 32 + quad * 8]);
            #pragma unroll
            for (int mt = 0; mt < 4; mt++)
                #pragma unroll
                for (int nt = 0; nt < 2; nt++)
                    acc[mt][nt] = __builtin_amdgcn_mfma_f32_16x16x32_bf16(a[mt], bw[kk][nt], acc[mt][nt], 0, 0, 0);
        }

        #pragma unroll
        for (int mt = 0; mt < 4; mt++) {
            #pragma unroll
            for (int q = 0; q < 4; q++) {
                int r = mt * 16 + quad * 4 + q;
                float s0 = 0.f, s1 = 0.f, s2 = 0.f;
                #pragma unroll
                for (int nt = 0; nt < 2; nt++) {
                    float v = fmaxf(acc[mt][nt][q] + b1v[nt], 0.f);
                    s0 += v * w2[nt][0]; s1 += v * w2[nt][1]; s2 += v * w2[nt][2];
                }
                #pragma unroll
                for (int d = 1; d < 16; d <<= 1) {
                    s0 += __shfl_xor(s0, d); s1 += __shfl_xor(s1, d); s2 += __shfl_xor(s2, d);
                }
                if (l15 == 0) { part[r][wave][0] = s0; part[r][wave][1] = s1; part[r][wave][2] = s2; }
            }
        }
        __syncthreads();

        for (int idx = tid; idx < 64 * 3; idx += 256) {
            int e = idx / 3, c = idx % 3;
            int oe = use_csr ? csr_eid[p0 + e] : (p0 + e);
            eout[(size_t)oe * 3 + c] =
                part[e][0][c] + part[e][1][c] + part[e][2][c] + part[e][3][c] + be2v[c];
        }
        __syncthreads();
    }
}

__global__ void gsum_kernel(const unsigned short* h, float* gsum) {
    int f = threadIdx.x;
    float local = 0.f;
    int n0 = blockIdx.x * 200;
    for (int j = 0; j < 200; j++) local += bf2f(h[(size_t)(n0 + j) * HDIM + f]);
    atomicAdd(&gsum[f], local);
}
__global__ void gout_kernel(const float* gsum, float* out) {
    int f = threadIdx.x;
    out[GEMB_OFF + f] = gsum[f] * (1.f / (float)NNODES);
}

extern "C" __attribute__((visibility("default")))
void kernel_launch(void* const* d_in, const int* in_sizes, int n_in,
                   void* d_out, int out_size, void* d_ws, size_t ws_size,
                   hipStream_t stream) {
    const void* x      = d_in[0];
    const int*  eidx   = (const int*)d_in[1];
    const void* W_emb  = d_in[2];
    const void* b_emb  = d_in[3];
    const void* gat_W  = d_in[4];
    const void* gat_as = d_in[5];
    const void* gat_ad = d_in[6];
    const void* gat_b  = d_in[7];
    const void* Wn1    = d_in[8];
    const void* bn1    = d_in[9];
    const void* Wn2    = d_in[10];
    const void* bn2    = d_in[11];
    const void* We1    = d_in[12];
    const void* be1    = d_in[13];
    const void* We2    = d_in[14];
    const void* be2    = d_in[15];
    float* out = (float*)d_out;   // output dtype: float32 (confirmed round 11)

    char* ws = (char*)d_ws;
    unsigned short* h       = (unsigned short*)(ws);                // 12.8 MB
    unsigned short* xw      = (unsigned short*)(ws + 12800000);     // 12.8 MB
    float*          alpha_s = (float*)(ws + 25600000);              // 200 KB
    float*          alpha_d = (float*)(ws + 25800000);              // 200 KB
    int*            cnt     = (int*)(ws + 26000000);                // 200 KB
    int*            off     = (int*)(ws + 26200000);                // 200 KB
    int*            bsum    = (int*)(ws + 26400000);                // 1 KB
    float*          gsum    = (float*)(ws + 26401024);              // 512 B
    int*            iflag   = (int*)(ws + 26401536);
    int*            fflag   = (int*)(ws + 26401540);
    float*          We1c    = (float*)(ws + 26402048);              // 128 KB
    float*          We2c    = (float*)(ws + 26533120);
    float*          asc     = (float*)(ws + 26534656);
    float*          adc     = (float*)(ws + 26536192);
    float*          gbc     = (float*)(ws + 26537728);
    float*          bembc   = (float*)(ws + 26539264);
    float*          bn1c    = (float*)(ws + 26539776);
    float*          bn2c    = (float*)(ws + 26540288);
    float*          be1c    = (float*)(ws + 26540544);
    float*          be2c    = (float*)(ws + 26541056);
    float*          Wlc     = (float*)(ws + 26542080);              // 64 KB
    int*            csr_src = (int*)(ws + 26608000);                // 3.2 MB -> 29.81 MB (proven)
    int*            csr_dst = (int*)(ws + 29808000);                // 3.2 MB (optional)
    int*            csr_eid = (int*)(ws + 33008000);                // 3.2 MB -> 36.21 MB (optional)

    // Only use the CSR-ordered edge-MLP path if the workspace can hold the
    // two extra 3.2 MB arrays. Otherwise stay within the proven 29.81 MB.
    const int use_csr = (ws_size >= (size_t)36208000) ? 1 : 0;

    const int node_blks = (NNODES + 255) / 256;    // 196
    const int edge_blks = (NEDGES + 255) / 256;    // 3125

    zero_int_kernel<<<1, 256, 0, stream>>>(iflag, 2);
    zero_int_kernel<<<node_blks, 256, 0, stream>>>(cnt, NNODES);
    zero_f32_kernel<<<1, 256, 0, stream>>>(gsum, HDIM);

    detect_f32_kernel<<<1, 256, 0, stream>>>((const unsigned short*)x, fflag);
    detect_i64_kernel<<<edge_blks, 256, 0, stream>>>(eidx, iflag);

    cvt_kernel<<<128, 256, 0, stream>>>(We1, We1c, 256 * 128, fflag);
    cvt_kernel<<<2, 256, 0, stream>>>(We2, We2c, 128 * 3, fflag);
    cvt_kernel<<<2, 256, 0, stream>>>(gat_as, asc, 3 * 128, fflag);
    cvt_kernel<<<2, 256, 0, stream>>>(gat_ad, adc, 3 * 128, fflag);
    cvt_kernel<<<2, 256, 0, stream>>>(gat_b, gbc, 3 * 128, fflag);
    cvt_kernel<<<1, 256, 0, stream>>>(b_emb, bembc, 128, fflag);
    cvt_kernel<<<1, 256, 0, stream>>>(bn1, bn1c, 128, fflag);
    cvt_kernel<<<1, 256, 0, stream>>>(bn2, bn2c, 64, fflag);
    cvt_kernel<<<1, 256, 0, stream>>>(be1, be1c, 128, fflag);
    cvt_kernel<<<1, 256, 0, stream>>>(be2, be2c, 3, fflag);

    // h = relu(x @ W_emb + b_emb)
    gemm128_kernel<<<(NNODES + 15) / 16, 256, 0, stream>>>(
        x, 1, W_emb, 0, bembc, h, 0, NNODES, 1, fflag);

    // CSR build (once)
    count_kernel<<<edge_blks, 256, 0, stream>>>(eidx, iflag, cnt);
    scan1_kernel<<<node_blks, 256, 0, stream>>>(cnt, off, bsum);
    scan2_kernel<<<1, 64, 0, stream>>>(bsum, node_blks);
    scan3_kernel<<<node_blks, 256, 0, stream>>>(off, bsum);
    zero_int_kernel<<<node_blks, 256, 0, stream>>>(cnt, NNODES);
    fill_kernel<<<edge_blks, 256, 0, stream>>>(eidx, iflag, off, cnt,
                                               csr_src, csr_dst, csr_eid, use_csr);

    for (int l = 0; l < NLAYERS; l++) {
        cvt_layerW_kernel<<<64, 256, 0, stream>>>(gat_W, Wlc, l, fflag);
        gemm128_kernel<<<(NNODES + 15) / 16, 256, 0, stream>>>(
            h, 0, Wlc, 1, (const float*)0, xw, 0, NNODES, 0, fflag);
        alpha_kernel<<<(NNODES + 3) / 4, 256, 0, stream>>>(
            xw, asc + l * HDIM, adc + l * HDIM, alpha_s, alpha_d);
        aggregate_kernel<<<(NNODES + 3) / 4, 256, 0, stream>>>(
            xw, alpha_s, alpha_d, off, csr_src, gbc + l * HDIM, h);
    }

    // node MLP
    gemm128_kernel<<<(NNODES + 15) / 16, 256, 0, stream>>>(
        h, 0, Wn1, 0, bn1c, xw, 0, NNODES, 1, fflag);
    gemm_any_kernel<<<(NNODES + 3) / 4, 256, 0, stream>>>(
        xw, 0, Wn2, 0, bn2c, out, 1, NNODES, 64, 0, fflag);

    // edge MLP (MFMA; CSR-ordered when workspace allows)
    edge_mlp_mfma_kernel<<<3125, 256, 0, stream>>>(
        h, eidx, iflag, csr_src, csr_dst, csr_eid, use_csr,
        We1c, be1c, We2c, be2c, out + NODE_OUT_ELEMS);

    // graph embedding
    gsum_kernel<<<NNODES / 200, 128, 0, stream>>>(h, gsum);
    gout_kernel<<<1, 128, 0, stream>>>(gsum, out);
}

// Round 3
// 914.352 us; speedup vs baseline: 1.6454x; 1.1734x over previous
//
#include <hip/hip_runtime.h>

#define NNODES 50000
#define NEDGES 800000
#define HDIM 128
#define DOUT 64
#define NLAYERS 3
#define NEG_SLOPE 0.2f

#define NODE_OUT_ELEMS (NNODES * DOUT)             // 3,200,000
#define EDGE_OUT_ELEMS (NEDGES * 3)                // 2,400,000
#define GEMB_OFF (NODE_OUT_ELEMS + EDGE_OUT_ELEMS) // 5,600,000

typedef __attribute__((ext_vector_type(8))) short short8;
typedef __attribute__((ext_vector_type(4))) float f32x4;

__device__ __forceinline__ float bf2f(unsigned short u) {
    union { unsigned int i; float f; } v; v.i = ((unsigned int)u) << 16; return v.f;
}
__device__ __forceinline__ unsigned short f2bf(float f) {
    union { unsigned int i; float f; } v; v.f = f;
    unsigned int b = v.i;
    unsigned int r = (b + 0x7FFFu + ((b >> 16) & 1u)) >> 16;
    return (unsigned short)r;
}
__device__ __forceinline__ float leaky(float x) { return x > 0.f ? x : NEG_SLOPE * x; }

// Edge fetch: which=0 -> src, which=1 -> dst. iflag=1 -> int32, 0 -> int64.
__device__ __forceinline__ int eget(const int* e32, const int* iflag, int which, int e) {
    int idx = which * NEDGES + e;
    return (*iflag) ? e32[idx] : e32[2 * idx];
}

__global__ void zero_int_kernel(int* p, int n) {
    int i = blockIdx.x * 256 + threadIdx.x;
    if (i < n) p[i] = 0;
}
__global__ void zero_f32_kernel(float* p, int n) {
    int i = blockIdx.x * 256 + threadIdx.x;
    if (i < n) p[i] = 0.f;
}

__global__ void detect_f32_kernel(const unsigned short* xb, int* flag) {
    int hit = 0;
    for (int j = threadIdx.x; j < 4096; j += 256) {
        int e = (xb[j] >> 7) & 0xFF;
        if (e >= 0x90) hit = 1;
    }
    if (hit) atomicOr(flag, 1);
}
__global__ void detect_i64_kernel(const int* e32, int* flag) {
    int i = blockIdx.x * 256 + threadIdx.x;
    if (i < NEDGES) {
        if (e32[2 * i + 1] != 0) atomicOr(flag, 1);
    }
}

__global__ void cvt_kernel(const void* src, float* dst, int n, const int* f32flag) {
    int i = blockIdx.x * 256 + threadIdx.x;
    if (i < n)
        dst[i] = (*f32flag) ? ((const float*)src)[i]
                            : bf2f(((const unsigned short*)src)[i]);
}
__global__ void cvt_layerW_kernel(const void* gat_W, float* dst, int l,
                                  const int* f32flag) {
    int i = blockIdx.x * 256 + threadIdx.x;
    if (i < HDIM * HDIM) {
        size_t idx = (size_t)l * HDIM * HDIM + i;
        dst[i] = (*f32flag) ? ((const float*)gat_W)[idx]
                            : bf2f(((const unsigned short*)gat_W)[idx]);
    }
}

// ---------------------------------------------------------------------------
// Generic scalar GEMM kept only for N=64 (node MLP layer 2).
// ---------------------------------------------------------------------------
__global__ void gemm_any_kernel(const void* Av, int a_dyn, const void* Bv,
                                int b_pre_f32, const float* bias,
                                void* Cv, int out_f32,
                                int M, int N, int relu, const int* f32flag) {
    const int f32 = *f32flag;
    const int a_f32 = a_dyn ? f32 : 0;
    const int b_f32 = b_pre_f32 ? 1 : f32;
    __shared__ float sA[4 * 128];
    const int tid = threadIdx.x;
    const int rpb = 256 / N;
    const int row0 = blockIdx.x * rpb;

    for (int i = tid; i < rpb * 128; i += 256) {
        int r = i >> 7, k = i & 127;
        int gr = row0 + r;
        float v = 0.f;
        if (gr < M) {
            if (a_f32) v = ((const float*)Av)[(size_t)gr * 128 + k];
            else       v = bf2f(((const unsigned short*)Av)[(size_t)gr * 128 + k]);
        }
        sA[i] = v;
    }
    __syncthreads();

    const int r = tid / N, col = tid % N;
    const int row = row0 + r;
    if (row < M) {
        float acc = bias ? bias[col] : 0.f;
        const float* a = &sA[r * 128];
        if (b_f32) {
            const float* B = (const float*)Bv;
            for (int k = 0; k < 128; k++) acc += a[k] * B[(size_t)k * N + col];
        } else {
            const unsigned short* B = (const unsigned short*)Bv;
            for (int k = 0; k < 128; k++) acc += a[k] * bf2f(B[(size_t)k * N + col]);
        }
        if (relu) acc = fmaxf(acc, 0.f);
        if (out_f32) ((float*)Cv)[(size_t)row * N + col] = acc;
        else         ((unsigned short*)Cv)[(size_t)row * N + col] = f2bf(acc);
    }
}

// ---------------------------------------------------------------------------
// Tiled GEMM for N=128: 16 rows/block, 8 accumulators/thread.
// In-place safe (Cv == Av): each block stages its 16 rows to LDS before
// any write, and blocks touch disjoint row ranges.
// ---------------------------------------------------------------------------
__global__ __launch_bounds__(256) void gemm128_kernel(
    const void* Av, int a_dyn, const void* Bv, int b_pre_f32,
    const float* bias, void* Cv, int out_f32, int M, int relu,
    const int* f32flag) {
    const int f32 = *f32flag;
    const int a_f32 = a_dyn ? f32 : 0;
    const int b_f32 = b_pre_f32 ? 1 : f32;
    __shared__ float sA[16 * 128];
    const int tid = threadIdx.x;
    const int row0 = blockIdx.x * 16;

    for (int i = tid; i < 16 * 128; i += 256) {
        int r = i >> 7, k = i & 127;
        int gr = row0 + r;
        float v = 0.f;
        if (gr < M) {
            if (a_f32) v = ((const float*)Av)[(size_t)gr * 128 + k];
            else       v = bf2f(((const unsigned short*)Av)[(size_t)gr * 128 + k]);
        }
        sA[i] = v;
    }
    __syncthreads();

    const int col = tid & 127;
    const int rg  = tid >> 7;       // 0 or 1: rows rg*8 .. rg*8+7
    float acc[8];
    float b0 = bias ? bias[col] : 0.f;
    #pragma unroll
    for (int r8 = 0; r8 < 8; r8++) acc[r8] = b0;

    if (b_f32) {
        const float* B = (const float*)Bv;
        for (int k = 0; k < 128; k++) {
            float bv = B[(size_t)k * 128 + col];
            #pragma unroll
            for (int r8 = 0; r8 < 8; r8++)
                acc[r8] += sA[(rg * 8 + r8) * 128 + k] * bv;
        }
    } else {
        const unsigned short* B = (const unsigned short*)Bv;
        for (int k = 0; k < 128; k++) {
            float bv = bf2f(B[(size_t)k * 128 + col]);
            #pragma unroll
            for (int r8 = 0; r8 < 8; r8++)
                acc[r8] += sA[(rg * 8 + r8) * 128 + k] * bv;
        }
    }

    #pragma unroll
    for (int r8 = 0; r8 < 8; r8++) {
        int row = row0 + rg * 8 + r8;
        if (row < M) {
            float a = acc[r8];
            if (relu) a = fmaxf(a, 0.f);
            if (out_f32) ((float*)Cv)[(size_t)row * 128 + col] = a;
            else         ((unsigned short*)Cv)[(size_t)row * 128 + col] = f2bf(a);
        }
    }
}

__global__ void alpha_kernel(const unsigned short* xw,
                             const float* a_s, const float* a_d,
                             float* alpha_s, float* alpha_d) {
    int wave = threadIdx.x >> 6, lane = threadIdx.x & 63;
    int n = blockIdx.x * 4 + wave;
    if (n >= NNODES) return;
    float v0 = bf2f(xw[(size_t)n * HDIM + lane]);
    float v1 = bf2f(xw[(size_t)n * HDIM + 64 + lane]);
    float ds = v0 * a_s[lane] + v1 * a_s[64 + lane];
    float dd = v0 * a_d[lane] + v1 * a_d[64 + lane];
    for (int d = 32; d >= 1; d >>= 1) { ds += __shfl_xor(ds, d); dd += __shfl_xor(dd, d); }
    if (lane == 0) { alpha_s[n] = ds; alpha_d[n] = dd; }
}

// ---- CSR build (group edges by dst) ----
__global__ void count_kernel(const int* e32, const int* iflag, int* cnt) {
    int e = blockIdx.x * 256 + threadIdx.x;
    if (e < NEDGES) atomicAdd(&cnt[eget(e32, iflag, 1, e)], 1);
}
__global__ void scan1_kernel(const int* cnt, int* off, int* bsum) {
    __shared__ int s[256];
    int t = threadIdx.x, i = blockIdx.x * 256 + t;
    int v = (i < NNODES) ? cnt[i] : 0;
    s[t] = v;
    __syncthreads();
    for (int d = 1; d < 256; d <<= 1) {
        int add = (t >= d) ? s[t - d] : 0;
        __syncthreads();
        s[t] += add;
        __syncthreads();
    }
    if (i < NNODES) off[i] = s[t] - v;          // exclusive
    if (t == 255) bsum[blockIdx.x] = s[255];
}
__global__ void scan2_kernel(int* bsum, int nblk) {
    if (threadIdx.x == 0 && blockIdx.x == 0) {
        int run = 0;
        for (int c = 0; c < nblk; c++) { int t = bsum[c]; bsum[c] = run; run += t; }
    }
}
__global__ void scan3_kernel(int* off, const int* bsum) {
    int i = blockIdx.x * 256 + threadIdx.x;
    if (i < NNODES) off[i] += bsum[blockIdx.x];
}
// use_csr: also record dst + original edge id (only when workspace allows)
__global__ void fill_kernel(const int* e32, const int* iflag, const int* off,
                            int* cur, int* csr_src, int* csr_dst, int* csr_eid,
                            int use_csr) {
    int e = blockIdx.x * 256 + threadIdx.x;
    if (e < NEDGES) {
        int sidx = eget(e32, iflag, 0, e);
        int d = eget(e32, iflag, 1, e);
        int p = atomicAdd(&cur[d], 1);
        int pos = off[d] + p;
        csr_src[pos] = sidx;
        if (use_csr) {
            csr_dst[pos] = d;
            csr_eid[pos] = e;
        }
    }
}

// GAT aggregation (gather): one wave per node; h = relu(h + agg + b) in place.
// 64 lanes = 4 edge-slots x 16 feature-lanes. Up to 64 edge indices AND their
// alpha_s values are prefetched lane-parallel and broadcast via __shfl —
// removes the 2-level dependent-load chain from the hot loop; only the xw
// row gather remains. Per-slot accumulation order identical to prior version.
__global__ void aggregate_kernel(const unsigned short* __restrict__ xw,
                                 const float* __restrict__ as_, const float* __restrict__ ad_,
                                 const int* __restrict__ off, const int* __restrict__ csr_src,
                                 const float* __restrict__ gat_b, unsigned short* __restrict__ h) {
    int wave = threadIdx.x >> 6, lane = threadIdx.x & 63;
    int n = blockIdx.x * 4 + wave;
    if (n >= NNODES) return;
    int o0 = off[n];
    int o1 = (n == NNODES - 1) ? NEDGES : off[n + 1];
    int deg = o1 - o0;
    float adn = ad_[n];
    float lself = leaky(as_[n] + adn);

    int deg64 = deg < 64 ? deg : 64;
    int idxv = 0; float av = 0.f;
    if (lane < deg64) { idxv = csr_src[o0 + lane]; av = as_[idxv]; }

    // running max over incoming-edge logits (same per-lane order as before)
    float m = lself;
    if (lane < deg64) m = fmaxf(m, leaky(av + adn));
    for (int i = 64 + lane; i < deg; i += 64) {
        int s = csr_src[o0 + i];
        m = fmaxf(m, leaky(as_[s] + adn));
    }
    #pragma unroll
    for (int d = 32; d >= 1; d >>= 1) m = fmaxf(m, __shfl_xor(m, d));

    const int slot = lane >> 4;     // which of 4 concurrent edges
    const int l15  = lane & 15;     // feature group: 8 bf16 = 16B per lane
    float denom = 0.f;
    float acc[8];
    #pragma unroll
    for (int k = 0; k < 8; k++) acc[k] = 0.f;

    // main loop: uniform bound, prefetched idx/alpha via shfl broadcast
    for (int t0 = 0; t0 < deg64; t0 += 4) {
        int i = t0 + slot;                  // i <= 63 always
        int sidx   = __shfl(idxv, i);
        float aval = __shfl(av, i);
        if (i < deg64) {
            float p = __expf(leaky(aval + adn) - m);
            denom += p;
            uint4 rv = *(const uint4*)(xw + (size_t)sidx * HDIM + l15 * 8);
            const unsigned short* rp = (const unsigned short*)&rv;
            #pragma unroll
            for (int k = 0; k < 8; k++) acc[k] += p * bf2f(rp[k]);
        }
    }
    // tail (deg > 64): continues the same i = slot (mod 4) sequence
    for (int i = 64 + slot; i < deg; i += 4) {
        int s = csr_src[o0 + i];
        float p = __expf(leaky(as_[s] + adn) - m);
        denom += p;
        uint4 rv = *(const uint4*)(xw + (size_t)s * HDIM + l15 * 8);
        const unsigned short* rp = (const unsigned short*)&rv;
        #pragma unroll
        for (int k = 0; k < 8; k++) acc[k] += p * bf2f(rp[k]);
    }

    // reduce across the 4 edge-slots (lane^16, lane^32)
    #pragma unroll
    for (int d = 16; d <= 32; d <<= 1) {
        denom += __shfl_xor(denom, d);
        #pragma unroll
        for (int k = 0; k < 8; k++) acc[k] += __shfl_xor(acc[k], d);
    }

    // self-loop (after the cross-slot reduce; all lanes hold full sums)
    float ps = __expf(lself - m);
    denom += ps;
    uint4 sv = *(const uint4*)(xw + (size_t)n * HDIM + l15 * 8);
    const unsigned short* sp = (const unsigned short*)&sv;
    #pragma unroll
    for (int k = 0; k < 8; k++) acc[k] += ps * bf2f(sp[k]);

    if (slot == 0) {
        float inv = 1.f / denom;
        size_t base = (size_t)n * HDIM + l15 * 8;
        uint4 hv = *(const uint4*)(h + base);
        const unsigned short* hp = (const unsigned short*)&hv;
        unsigned short outv[8];
        #pragma unroll
        for (int k = 0; k < 8; k++) {
            float hx = bf2f(hp[k]);
            float bx = gat_b[l15 * 8 + k];
            outv[k] = f2bf(fmaxf(hx + acc[k] * inv + bx, 0.f));
        }
        *(uint4*)(h + base) = *(uint4*)outv;
    }
}

// ---------------------------------------------------------------------------
// Edge MLP via algebraic split:
//   concat(h[s],h[d]) @ We1 + be1 == (h[s]@We1_top + be1) + (h[d]@We1_bot)
// A[n] = h@We1_top + be1, B[n] = h@We1_bot precomputed per node (gemm128).
// Per edge: v = relu(A[src]+B[dst]); out = v @ We2 + be2.
// 16 lanes per edge, 4 edges per wave. Barrier-free, streaming, no LDS.
// ---------------------------------------------------------------------------
__global__ __launch_bounds__(256) void edge_split_kernel(
    const unsigned short* __restrict__ A, const unsigned short* __restrict__ B,
    const int* __restrict__ e32, const int* __restrict__ iflag,
    const int* __restrict__ csr_src, const int* __restrict__ csr_dst,
    const int* __restrict__ csr_eid, int use_csr,
    const float* __restrict__ We2, const float* __restrict__ be2,
    float* __restrict__ eout)
{
    const int lane = threadIdx.x & 63;
    const int slot = lane >> 4, l15 = lane & 15;

    float w2[8][3];
    #pragma unroll
    for (int j = 0; j < 8; j++)
        #pragma unroll
        for (int c = 0; c < 3; c++)
            w2[j][c] = We2[(l15 * 8 + j) * 3 + c];
    const float bo0 = be2[0], bo1 = be2[1], bo2 = be2[2];

    const int gw = (blockIdx.x * 256 + threadIdx.x) >> 6;   // global wave id
    const int stride = gridDim.x * 16;                      // edges per sweep
    for (int e = gw * 4 + slot; e < NEDGES; e += stride) {
        int s, d, oe;
        if (use_csr) { s = csr_src[e]; d = csr_dst[e]; oe = csr_eid[e]; }
        else {
            s = eget(e32, iflag, 0, e);
            d = eget(e32, iflag, 1, e);
            oe = e;
        }
        uint4 avv = *(const uint4*)(A + (size_t)s * HDIM + l15 * 8);
        uint4 bvv = *(const uint4*)(B + (size_t)d * HDIM + l15 * 8);
        const unsigned short* ap = (const unsigned short*)&avv;
        const unsigned short* bp = (const unsigned short*)&bvv;
        float s0 = 0.f, s1 = 0.f, s2 = 0.f;
        #pragma unroll
        for (int j = 0; j < 8; j++) {
            float v = fmaxf(bf2f(ap[j]) + bf2f(bp[j]), 0.f);
            s0 += v * w2[j][0]; s1 += v * w2[j][1]; s2 += v * w2[j][2];
        }
        #pragma unroll
        for (int dd = 1; dd < 16; dd <<= 1) {
            s0 += __shfl_xor(s0, dd);
            s1 += __shfl_xor(s1, dd);
            s2 += __shfl_xor(s2, dd);
        }
        if (l15 == 0) {
            eout[(size_t)oe * 3 + 0] = s0 + bo0;
            eout[(size_t)oe * 3 + 1] = s1 + bo1;
            eout[(size_t)oe * 3 + 2] = s2 + bo2;
        }
    }
}

__global__ void gsum_kernel(const unsigned short* h, float* gsum) {
    int f = threadIdx.x;
    float local = 0.f;
    int n0 = blockIdx.x * 200;
    for (int j = 0; j < 200; j++) local += bf2f(h[(size_t)(n0 + j) * HDIM + f]);
    atomicAdd(&gsum[f], local);
}
__global__ void gout_kernel(const float* gsum, float* out) {
    int f = threadIdx.x;
    out[GEMB_OFF + f] = gsum[f] * (1.f / (float)NNODES);
}

extern "C" __attribute__((visibility("default")))
void kernel_launch(void* const* d_in, const int* in_sizes, int n_in,
                   void* d_out, int out_size, void* d_ws, size_t ws_size,
                   hipStream_t stream) {
    const void* x      = d_in[0];
    const int*  eidx   = (const int*)d_in[1];
    const void* W_emb  = d_in[2];
    const void* b_emb  = d_in[3];
    const void* gat_W  = d_in[4];
    const void* gat_as = d_in[5];
    const void* gat_ad = d_in[6];
    const void* gat_b  = d_in[7];
    const void* Wn1    = d_in[8];
    const void* bn1    = d_in[9];
    const void* Wn2    = d_in[10];
    const void* bn2    = d_in[11];
    const void* We1    = d_in[12];
    const void* be1    = d_in[13];
    const void* We2    = d_in[14];
    const void* be2    = d_in[15];
    float* out = (float*)d_out;   // output dtype: float32 (confirmed round 11)

    char* ws = (char*)d_ws;
    unsigned short* h       = (unsigned short*)(ws);                // 12.8 MB
    unsigned short* xw      = (unsigned short*)(ws + 12800000);     // 12.8 MB
    float*          alpha_s = (float*)(ws + 25600000);              // 200 KB
    float*          alpha_d = (float*)(ws + 25800000);              // 200 KB
    int*            cnt     = (int*)(ws + 26000000);                // 200 KB
    int*            off     = (int*)(ws + 26200000);                // 200 KB
    int*            bsum    = (int*)(ws + 26400000);                // 1 KB
    float*          gsum    = (float*)(ws + 26401024);              // 512 B
    int*            iflag   = (int*)(ws + 26401536);
    int*            fflag   = (int*)(ws + 26401540);
    float*          We1c    = (float*)(ws + 26402048);              // 128 KB
    float*          We2c    = (float*)(ws + 26533120);
    float*          asc     = (float*)(ws + 26534656);
    float*          adc     = (float*)(ws + 26536192);
    float*          gbc     = (float*)(ws + 26537728);
    float*          bembc   = (float*)(ws + 26539264);
    float*          bn1c    = (float*)(ws + 26539776);
    float*          bn2c    = (float*)(ws + 26540288);
    float*          be1c    = (float*)(ws + 26540544);
    float*          be2c    = (float*)(ws + 26541056);
    float*          Wlc     = (float*)(ws + 26542080);              // 64 KB
    int*            csr_src = (int*)(ws + 26608000);                // 3.2 MB -> 29.81 MB (proven)
    int*            csr_dst = (int*)(ws + 29808000);                // 3.2 MB (optional)
    int*            csr_eid = (int*)(ws + 33008000);                // 3.2 MB -> 36.21 MB (optional)

    // CSR-ordered edge path only if workspace holds the two extra arrays.
    const int use_csr = (ws_size >= (size_t)36208000) ? 1 : 0;

    const int node_blks = (NNODES + 255) / 256;    // 196
    const int edge_blks = (NEDGES + 255) / 256;    // 3125

    zero_int_kernel<<<1, 256, 0, stream>>>(iflag, 2);
    zero_int_kernel<<<node_blks, 256, 0, stream>>>(cnt, NNODES);
    zero_f32_kernel<<<1, 256, 0, stream>>>(gsum, HDIM);

    detect_f32_kernel<<<1, 256, 0, stream>>>((const unsigned short*)x, fflag);
    detect_i64_kernel<<<edge_blks, 256, 0, stream>>>(eidx, iflag);

    cvt_kernel<<<128, 256, 0, stream>>>(We1, We1c, 256 * 128, fflag);
    cvt_kernel<<<2, 256, 0, stream>>>(We2, We2c, 128 * 3, fflag);
    cvt_kernel<<<2, 256, 0, stream>>>(gat_as, asc, 3 * 128, fflag);
    cvt_kernel<<<2, 256, 0, stream>>>(gat_ad, adc, 3 * 128, fflag);
    cvt_kernel<<<2, 256, 0, stream>>>(gat_b, gbc, 3 * 128, fflag);
    cvt_kernel<<<1, 256, 0, stream>>>(b_emb, bembc, 128, fflag);
    cvt_kernel<<<1, 256, 0, stream>>>(bn1, bn1c, 128, fflag);
    cvt_kernel<<<1, 256, 0, stream>>>(bn2, bn2c, 64, fflag);
    cvt_kernel<<<1, 256, 0, stream>>>(be1, be1c, 128, fflag);
    cvt_kernel<<<1, 256, 0, stream>>>(be2, be2c, 3, fflag);

    // h = relu(x @ W_emb + b_emb)
    gemm128_kernel<<<(NNODES + 15) / 16, 256, 0, stream>>>(
        x, 1, W_emb, 0, bembc, h, 0, NNODES, 1, fflag);

    // CSR build (once)
    count_kernel<<<edge_blks, 256, 0, stream>>>(eidx, iflag, cnt);
    scan1_kernel<<<node_blks, 256, 0, stream>>>(cnt, off, bsum);
    scan2_kernel<<<1, 64, 0, stream>>>(bsum, node_blks);
    scan3_kernel<<<node_blks, 256, 0, stream>>>(off, bsum);
    zero_int_kernel<<<node_blks, 256, 0, stream>>>(cnt, NNODES);
    fill_kernel<<<edge_blks, 256, 0, stream>>>(eidx, iflag, off, cnt,
                                               csr_src, csr_dst, csr_eid, use_csr);

    for (int l = 0; l < NLAYERS; l++) {
        cvt_layerW_kernel<<<64, 256, 0, stream>>>(gat_W, Wlc, l, fflag);
        gemm128_kernel<<<(NNODES + 15) / 16, 256, 0, stream>>>(
            h, 0, Wlc, 1, (const float*)0, xw, 0, NNODES, 0, fflag);
        alpha_kernel<<<(NNODES + 3) / 4, 256, 0, stream>>>(
            xw, asc + l * HDIM, adc + l * HDIM, alpha_s, alpha_d);
        aggregate_kernel<<<(NNODES + 3) / 4, 256, 0, stream>>>(
            xw, alpha_s, alpha_d, off, csr_src, gbc + l * HDIM, h);
    }

    // node MLP
    gemm128_kernel<<<(NNODES + 15) / 16, 256, 0, stream>>>(
        h, 0, Wn1, 0, bn1c, xw, 0, NNODES, 1, fflag);
    gemm_any_kernel<<<(NNODES + 3) / 4, 256, 0, stream>>>(
        xw, 0, Wn2, 0, bn2c, out, 1, NNODES, 64, 0, fflag);

    // graph embedding (must precede the in-place B GEMM that overwrites h)
    gsum_kernel<<<NNODES / 200, 128, 0, stream>>>(h, gsum);
    gout_kernel<<<1, 128, 0, stream>>>(gsum, out);

    // edge MLP via split: A = h@We1_top + be1 -> xw (free after node MLP);
    //                     B = h@We1_bot       -> h (in-place)
    gemm128_kernel<<<(NNODES + 15) / 16, 256, 0, stream>>>(
        h, 0, We1c, 1, be1c, xw, 0, NNODES, 0, fflag);
    gemm128_kernel<<<(NNODES + 15) / 16, 256, 0, stream>>>(
        h, 0, We1c + 128 * 128, 1, (const float*)0, h, 0, NNODES, 0, fflag);
    edge_split_kernel<<<2048, 256, 0, stream>>>(
        xw, h, eidx, iflag, csr_src, csr_dst, csr_eid, use_csr,
        We2c, be2c, out + NODE_OUT_ELEMS);
}